// Round 1
// baseline (763.658 us; speedup 1.0000x reference)
//
#include <hip/hip_runtime.h>
#include <math.h>

// ---------------------------------------------------------------------------
// QuantumCritic: x=[state|action](B,128) -> h=relu(x@w1+b1)(B,256)
//   -> enc=h@w2+b2 (B,8) -> 8-qubit circuit -> ex (B,8)
//   -> h2=relu(ex@w3+b3)(B,256) -> q=h2@w4+b4 (B,1).  Two critics (a,b).
// Strategy:
//   prep_gates: fuse Rz*Ry*Rx per (layer,qubit) into one 2x2 complex unitary.
//   enc_kernel: fp32 tiled GEMM (BM=64, N=256, K=128) fused with h@w2 epilogue.
//   quantum_kernel: one wave per batch element; 256 amplitudes = 4 complex/lane;
//     cross-lane gates via __shfl_xor; CNOTs are permutations; fused final MLP.
// ---------------------------------------------------------------------------

struct C2 { float r, i; };
__device__ __forceinline__ C2 cmul(C2 a, C2 b){ return C2{a.r*b.r - a.i*b.i, a.r*b.i + a.i*b.r}; }
__device__ __forceinline__ C2 cadd(C2 a, C2 b){ return C2{a.r+b.r, a.i+b.i}; }

// gates[(c*24 + l*8 + q)*8] = {u00r,u00i,u01r,u01i,u10r,u10i,u11r,u11i}
__global__ void prep_gates(const float* __restrict__ qrxa, const float* __restrict__ qrya,
                           const float* __restrict__ qrza,
                           const float* __restrict__ qrxb, const float* __restrict__ qryb,
                           const float* __restrict__ qrzb,
                           float* __restrict__ gates) {
  int t = threadIdx.x;
  if (t >= 48) return;
  int c = t / 24, g = t % 24;   // g = l*8 + i, qr* are (3,8) row-major
  const float* qx = c ? qrxb : qrxa;
  const float* qy = c ? qryb : qrya;
  const float* qz = c ? qrzb : qrza;
  float tx = 0.5f*qx[g], ty = 0.5f*qy[g], tz = 0.5f*qz[g];
  float cx = cosf(tx), sx = sinf(tx);
  float cy = cosf(ty), sy = sinf(ty);
  float cz = cosf(tz), sz = sinf(tz);
  // Rx = [[(cx,0),(0,-sx)],[(0,-sx),(cx,0)]] ; Ry = [[(cy,0),(-sy,0)],[(sy,0),(cy,0)]]
  C2 rx00{cx,0.f}, rx01{0.f,-sx}, rx10{0.f,-sx}, rx11{cx,0.f};
  C2 m00 = cadd(cmul(C2{cy,0.f},rx00), cmul(C2{-sy,0.f},rx10));
  C2 m01 = cadd(cmul(C2{cy,0.f},rx01), cmul(C2{-sy,0.f},rx11));
  C2 m10 = cadd(cmul(C2{sy,0.f},rx00), cmul(C2{cy,0.f},rx10));
  C2 m11 = cadd(cmul(C2{sy,0.f},rx01), cmul(C2{cy,0.f},rx11));
  C2 e0{cz,-sz}, e1{cz,sz};   // Rz = diag(e^{-i t/2}, e^{+i t/2})
  C2 u00 = cmul(e0,m00), u01 = cmul(e0,m01), u10 = cmul(e1,m10), u11 = cmul(e1,m11);
  float* o = gates + (size_t)(c*24 + g)*8;
  o[0]=u00.r; o[1]=u00.i; o[2]=u01.r; o[3]=u01.i;
  o[4]=u10.r; o[5]=u10.i; o[6]=u11.r; o[7]=u11.i;
}

// ---------------------------------------------------------------------------
// enc kernel: per block, 64 batch rows. 256 threads as (tr=tid>>5 in [0,8), tc=tid&31).
// Thread tile 8 rows x 8 cols of h; K streamed in 4 slices of 32 through LDS.
// Epilogue: h@w2 partials reduced across tc via shfl, written as enc (B,8).
// ---------------------------------------------------------------------------
__global__ __launch_bounds__(256)
void enc_kernel(const float* __restrict__ state, const float* __restrict__ action,
                const float* __restrict__ w1a, const float* __restrict__ b1a,
                const float* __restrict__ w2a, const float* __restrict__ b2a,
                const float* __restrict__ w1b, const float* __restrict__ b1b,
                const float* __restrict__ w2b, const float* __restrict__ b2b,
                float* __restrict__ enc, int B) {
  __shared__ __align__(16) float xs[64*128];     // xs[r][k]
  __shared__ __align__(16) float wsl[32*256];    // wsl[kk][n]
  __shared__ __align__(16) float w2t[8*256];     // w2t[e][n]
  int tid = threadIdx.x;
  int r0 = blockIdx.x * 64;
  int tr = tid >> 5, tc = tid & 31;

  // stage x = [state(96) | action(32)]
  const float4* st4 = (const float4*)state;
  const float4* ac4 = (const float4*)action;
  for (int idx = tid; idx < 64*24; idx += 256) {
    int r = idx / 24, k4 = idx % 24;
    float4 v = st4[(size_t)(r0 + r)*24 + k4];
    ((float4*)&xs[r*128 + k4*4])[0] = v;
  }
  for (int idx = tid; idx < 64*8; idx += 256) {
    int r = idx >> 3, k4 = idx & 7;
    float4 v = ac4[(size_t)(r0 + r)*8 + k4];
    ((float4*)&xs[r*128 + 96 + k4*4])[0] = v;
  }

  for (int c = 0; c < 2; ++c) {
    const float* w1 = c ? w1b : w1a;
    const float* b1 = c ? b1b : b1a;
    const float* w2 = c ? w2b : w2a;
    const float* b2 = c ? b2b : b2a;
    float acc[8][8];
    #pragma unroll
    for (int rr = 0; rr < 8; ++rr)
      #pragma unroll
      for (int cc = 0; cc < 8; ++cc) acc[rr][cc] = 0.f;

    const float4* w1_4 = (const float4*)w1;
    for (int s = 0; s < 4; ++s) {
      __syncthreads();   // protect wsl readers (and xs staging on first pass)
      #pragma unroll
      for (int j = 0; j < 8; ++j) {
        int idx4 = tid + j*256;                 // 0..2047
        float4 v = w1_4[s*2048 + idx4];
        ((float4*)&wsl[idx4*4])[0] = v;
      }
      __syncthreads();
      #pragma unroll 4
      for (int kk = 0; kk < 32; ++kk) {
        float av[8], bv[8];
        #pragma unroll
        for (int rr = 0; rr < 8; ++rr) av[rr] = xs[(tr*8+rr)*128 + s*32 + kk];
        const float4* wp = (const float4*)&wsl[kk*256 + tc*8];
        float4 blo = wp[0], bhi = wp[1];
        bv[0]=blo.x; bv[1]=blo.y; bv[2]=blo.z; bv[3]=blo.w;
        bv[4]=bhi.x; bv[5]=bhi.y; bv[6]=bhi.z; bv[7]=bhi.w;
        #pragma unroll
        for (int rr = 0; rr < 8; ++rr)
          #pragma unroll
          for (int cc = 0; cc < 8; ++cc) acc[rr][cc] = fmaf(av[rr], bv[cc], acc[rr][cc]);
      }
    }

    // ---- epilogue: h = relu(acc + b1), penc = h @ w2 ----
    __syncthreads();
    for (int idx = tid; idx < 2048; idx += 256) {
      int n = idx >> 3, e = idx & 7;
      w2t[e*256 + n] = w2[idx];
    }
    __syncthreads();
    float b1v[8];
    #pragma unroll
    for (int cc = 0; cc < 8; ++cc) b1v[cc] = b1[tc*8 + cc];
    #pragma unroll
    for (int rr = 0; rr < 8; ++rr)
      #pragma unroll
      for (int cc = 0; cc < 8; ++cc) acc[rr][cc] = fmaxf(acc[rr][cc] + b1v[cc], 0.f);

    float penc[8][8];
    #pragma unroll
    for (int rr = 0; rr < 8; ++rr)
      #pragma unroll
      for (int e = 0; e < 8; ++e) penc[rr][e] = 0.f;
    #pragma unroll
    for (int e = 0; e < 8; ++e) {
      const float4* wp = (const float4*)&w2t[e*256 + tc*8];
      float4 wlo = wp[0], whi = wp[1];
      float wv[8] = {wlo.x,wlo.y,wlo.z,wlo.w,whi.x,whi.y,whi.z,whi.w};
      #pragma unroll
      for (int rr = 0; rr < 8; ++rr)
        #pragma unroll
        for (int cc = 0; cc < 8; ++cc) penc[rr][e] = fmaf(acc[rr][cc], wv[cc], penc[rr][e]);
    }
    // reduce partials across the 32 tc-threads (lanes within 32-halves)
    #pragma unroll
    for (int mask = 1; mask <= 16; mask <<= 1)
      #pragma unroll
      for (int rr = 0; rr < 8; ++rr)
        #pragma unroll
        for (int e = 0; e < 8; ++e) penc[rr][e] += __shfl_xor(penc[rr][e], mask);
    if (tc == 0) {
      float b2v[8];
      #pragma unroll
      for (int e = 0; e < 8; ++e) b2v[e] = b2[e];
      #pragma unroll
      for (int rr = 0; rr < 8; ++rr) {
        int row = r0 + tr*8 + rr;
        float4* op = (float4*)(enc + ((size_t)c*B + row)*8);
        op[0] = make_float4(penc[rr][0]+b2v[0], penc[rr][1]+b2v[1],
                            penc[rr][2]+b2v[2], penc[rr][3]+b2v[3]);
        op[1] = make_float4(penc[rr][4]+b2v[4], penc[rr][5]+b2v[5],
                            penc[rr][6]+b2v[6], penc[rr][7]+b2v[7]);
      }
    }
  }
}

// ---------------------------------------------------------------------------
// quantum kernel: one wave per batch element. Amplitude index b (8 bits):
// qubit i <-> bit (7-i). lane = b>>2 (bits 7..2), local j = b&3 (bits 1..0).
// So qubit q in [0,5] <-> lane bit (5-q); qubit 6 <-> local bit1; qubit 7 <-> bit0.
// ---------------------------------------------------------------------------
#define APPLY2(A,Bx)                                                        \
  { float ar=re[A], ai=im[A], br=re[Bx], bi=im[Bx];                         \
    re[A]  = u00r*ar - u00i*ai + u01r*br - u01i*bi;                         \
    im[A]  = u00r*ai + u00i*ar + u01r*bi + u01i*br;                         \
    re[Bx] = u10r*ar - u10i*ai + u11r*br - u11i*bi;                         \
    im[Bx] = u10r*ai + u10i*ar + u11r*bi + u11i*br; }

__global__ __launch_bounds__(256)
void quantum_kernel(const float* __restrict__ enc, const float* __restrict__ gates,
                    const float* __restrict__ w3a, const float* __restrict__ b3a,
                    const float* __restrict__ w4a, const float* __restrict__ b4a,
                    const float* __restrict__ w3b, const float* __restrict__ b3b,
                    const float* __restrict__ w4b, const float* __restrict__ b4b,
                    float* __restrict__ out, int B) {
  __shared__ float sg[384];
  __shared__ float sw3[2][2048];
  __shared__ float sb3[2][256];
  __shared__ float sw4[2][256];
  __shared__ float sb4[2];
  int tid = threadIdx.x;
  for (int i = tid; i < 384; i += 256) sg[i] = gates[i];
  for (int i = tid; i < 2048; i += 256) { sw3[0][i] = w3a[i]; sw3[1][i] = w3b[i]; }
  { sb3[0][tid]=b3a[tid]; sb3[1][tid]=b3b[tid]; sw4[0][tid]=w4a[tid]; sw4[1][tid]=w4b[tid]; }
  if (tid == 0) { sb4[0]=b4a[0]; sb4[1]=b4b[0]; }
  __syncthreads();

  int lane = tid & 63;
  int elem = blockIdx.x*4 + (tid >> 6);
  if (elem >= B) return;
  float outq[2];

  for (int c = 0; c < 2; ++c) {
    // ---- encoded product state ----
    const float* ep = enc + ((size_t)c*B + elem)*8;
    float cs[8], sn[8];
    #pragma unroll
    for (int i = 0; i < 8; ++i) { float t = 0.5f*ep[i]; cs[i]=cosf(t); sn[i]=sinf(t); }
    float re[4], im[4];
    #pragma unroll
    for (int j = 0; j < 4; ++j) {
      int b = (lane<<2) | j;
      float r = 1.f;
      #pragma unroll
      for (int i = 0; i < 8; ++i) r *= ((b >> (7-i)) & 1) ? sn[i] : cs[i];
      int p = __popc(b) & 3;                        // phase (-i)^popcount
      re[j] = (p==0) ? r : ((p==2) ? -r : 0.f);
      im[j] = (p==1) ? -r : ((p==3) ? r : 0.f);
    }
    // ---- 3 layers of fused 1q gates + CNOT ring ----
    #pragma unroll
    for (int l = 0; l < 3; ++l) {
      #pragma unroll
      for (int q = 0; q < 8; ++q) {
        const float* u = &sg[(size_t)(c*24 + l*8 + q)*8];
        float u00r=u[0],u00i=u[1],u01r=u[2],u01i=u[3];
        float u10r=u[4],u10i=u[5],u11r=u[6],u11i=u[7];
        if (q < 6) {
          int m = 5-q, mask = 1<<m;
          bool s1 = ((lane >> m) & 1) != 0;
          float udr = s1?u11r:u00r, udi = s1?u11i:u00i;
          float uor = s1?u10r:u01r, uoi = s1?u10i:u01i;
          #pragma unroll
          for (int j = 0; j < 4; ++j) {
            float pr = __shfl_xor(re[j], mask);
            float pi = __shfl_xor(im[j], mask);
            float nr = udr*re[j] - udi*im[j] + uor*pr - uoi*pi;
            float ni = udr*im[j] + udi*re[j] + uor*pi + uoi*pr;
            re[j]=nr; im[j]=ni;
          }
        } else if (q == 6) { APPLY2(0,2); APPLY2(1,3); }
        else               { APPLY2(0,1); APPLY2(2,3); }
      }
      // CNOT(cq,cq+1) for cq=0..4: control lane-bit (5-cq), target lane-bit (4-cq)
      #pragma unroll
      for (int cq = 0; cq <= 4; ++cq) {
        int tmask = 1 << (4-cq);
        bool pred = ((lane >> (5-cq)) & 1) != 0;
        #pragma unroll
        for (int j = 0; j < 4; ++j) {
          float sr = __shfl_xor(re[j], tmask);
          float si = __shfl_xor(im[j], tmask);
          re[j] = pred ? sr : re[j];
          im[j] = pred ? si : im[j];
        }
      }
      { // CNOT(5,6): control lane-bit0, target local bit1 -> swap j 0<->2, 1<->3
        bool pred = (lane & 1) != 0;
        float t0, t1;
        t0 = pred?re[2]:re[0]; t1 = pred?re[0]:re[2]; re[0]=t0; re[2]=t1;
        t0 = pred?im[2]:im[0]; t1 = pred?im[0]:im[2]; im[0]=t0; im[2]=t1;
        t0 = pred?re[3]:re[1]; t1 = pred?re[1]:re[3]; re[1]=t0; re[3]=t1;
        t0 = pred?im[3]:im[1]; t1 = pred?im[1]:im[3]; im[1]=t0; im[3]=t1;
      }
      { // CNOT(6,7): control local bit1, target local bit0 -> swap j=2,3
        float t;
        t=re[2]; re[2]=re[3]; re[3]=t;
        t=im[2]; im[2]=im[3]; im[3]=t;
      }
      { // CNOT(7,0): control local bit0 (j=1,3), target lane-bit 5 -> exchange with lane^32
        re[1]=__shfl_xor(re[1],32); im[1]=__shfl_xor(im[1],32);
        re[3]=__shfl_xor(re[3],32); im[3]=__shfl_xor(im[3],32);
      }
    }
    // ---- measurement: ex[q] = sum_b sign_q(b) * |amp_b|^2 ----
    float p0 = re[0]*re[0]+im[0]*im[0];
    float p1 = re[1]*re[1]+im[1]*im[1];
    float p2 = re[2]*re[2]+im[2]*im[2];
    float p3 = re[3]*re[3]+im[3]*im[3];
    float tot = p0+p1+p2+p3;
    float exv[8];
    #pragma unroll
    for (int q = 0; q < 6; ++q) exv[q] = ((lane >> (5-q)) & 1) ? -tot : tot;
    exv[6] = p0+p1-p2-p3;
    exv[7] = p0-p1+p2-p3;
    #pragma unroll
    for (int mask = 1; mask <= 32; mask <<= 1)
      #pragma unroll
      for (int q = 0; q < 8; ++q) exv[q] += __shfl_xor(exv[q], mask);
    // ---- final MLP: q = relu(ex@w3+b3)@w4 + b4 ----
    float h2[4];
    #pragma unroll
    for (int j = 0; j < 4; ++j) h2[j] = sb3[c][lane + 64*j];
    #pragma unroll
    for (int k = 0; k < 8; ++k) {
      float e = exv[k];
      #pragma unroll
      for (int j = 0; j < 4; ++j) h2[j] = fmaf(e, sw3[c][k*256 + lane + 64*j], h2[j]);
    }
    float qp = 0.f;
    #pragma unroll
    for (int j = 0; j < 4; ++j) qp = fmaf(fmaxf(h2[j], 0.f), sw4[c][lane + 64*j], qp);
    #pragma unroll
    for (int mask = 1; mask <= 32; mask <<= 1) qp += __shfl_xor(qp, mask);
    outq[c] = qp + sb4[c];
  }
  if (lane == 0) {
    out[elem]     = outq[0];
    out[B + elem] = outq[1];
  }
}

extern "C" void kernel_launch(void* const* d_in, const int* in_sizes, int n_in,
                              void* d_out, int out_size, void* d_ws, size_t ws_size,
                              hipStream_t stream) {
  (void)n_in; (void)out_size; (void)ws_size;
  const float* state  = (const float*)d_in[0];
  const float* action = (const float*)d_in[1];
  const float* w1a=(const float*)d_in[2];  const float* b1a=(const float*)d_in[3];
  const float* w2a=(const float*)d_in[4];  const float* b2a=(const float*)d_in[5];
  const float* qrxa=(const float*)d_in[6]; const float* qrya=(const float*)d_in[7];
  const float* qrza=(const float*)d_in[8];
  const float* w3a=(const float*)d_in[9];  const float* b3a=(const float*)d_in[10];
  const float* w4a=(const float*)d_in[11]; const float* b4a=(const float*)d_in[12];
  const float* w1b=(const float*)d_in[13]; const float* b1b=(const float*)d_in[14];
  const float* w2b=(const float*)d_in[15]; const float* b2b=(const float*)d_in[16];
  const float* qrxb=(const float*)d_in[17];const float* qryb=(const float*)d_in[18];
  const float* qrzb=(const float*)d_in[19];
  const float* w3b=(const float*)d_in[20]; const float* b3b=(const float*)d_in[21];
  const float* w4b=(const float*)d_in[22]; const float* b4b=(const float*)d_in[23];

  int B = in_sizes[0] / 96;
  float* ws_f  = (float*)d_ws;
  float* gates = ws_f;          // 384 floats
  float* enc   = ws_f + 512;    // 2*B*8 floats

  prep_gates<<<1, 64, 0, stream>>>(qrxa,qrya,qrza,qrxb,qryb,qrzb,gates);
  enc_kernel<<<B/64, 256, 0, stream>>>(state,action,w1a,b1a,w2a,b2a,w1b,b1b,w2b,b2b,enc,B);
  quantum_kernel<<<(B+3)/4, 256, 0, stream>>>(enc,gates,w3a,b3a,w4a,b4a,w3b,b3b,w4b,b4b,
                                              (float*)d_out,B);
}

// Round 2
// 350.537 us; speedup vs baseline: 2.1785x; 2.1785x over previous
//
#include <hip/hip_runtime.h>
#include <math.h>

// ---------------------------------------------------------------------------
// QuantumCritic. Round 2: quantum layer as GEMM.
//   psi = U * psi0, psi0 = D * r  (D = diag((-i)^popc(b)) fixed, r REAL)
//   => psi = W r,  W = U*D fixed per critic (256x256 complex, bf16)
//   ex@w3 = P @ G,  P = |psi|^2 componentwise,  G = S^T w3 (fixed, bf16)
// Kernels:
//   prep_gates: fuse Rz*Ry*Rx per (layer,qubit) -> 2x2 unitaries.
//   gprep:      G[c][n][i] = sum_q sign_q(i) * w3[q][n]  (bf16).
//   prep_W:     circuit on 256 basis columns -> Bmat[c][n=512(re|im)][k=256] bf16.
//   enc_kernel: fp32 tiled GEMM (unchanged from R1) -> enc (2,B,8).
//   qgemm:      per 32-row subtile: build R in LDS (frag order) -> MFMA vs
//               in-register W-frags -> P in LDS -> MFMA vs G -> relu/w4 -> out.
// ---------------------------------------------------------------------------

typedef __attribute__((ext_vector_type(8))) short bfrag_t;   // 8 bf16 = 4 VGPR
typedef __attribute__((ext_vector_type(16))) float accv_t;   // 32x32 MFMA acc

__device__ __forceinline__ unsigned short f2bf(float x) {
  unsigned u = __float_as_uint(x);
  u += 0x7FFFu + ((u >> 16) & 1u);      // RNE
  return (unsigned short)(u >> 16);
}
__device__ __forceinline__ unsigned pack2(float a, float b) {
  return (unsigned)f2bf(a) | ((unsigned)f2bf(b) << 16);
}

struct C2 { float r, i; };
__device__ __forceinline__ C2 cmul(C2 a, C2 b){ return C2{a.r*b.r - a.i*b.i, a.r*b.i + a.i*b.r}; }
__device__ __forceinline__ C2 cadd(C2 a, C2 b){ return C2{a.r+b.r, a.i+b.i}; }

// gates[(c*24 + l*8 + q)*8] = {u00r,u00i,u01r,u01i,u10r,u10i,u11r,u11i}
__global__ void prep_gates(const float* __restrict__ qrxa, const float* __restrict__ qrya,
                           const float* __restrict__ qrza,
                           const float* __restrict__ qrxb, const float* __restrict__ qryb,
                           const float* __restrict__ qrzb,
                           float* __restrict__ gates) {
  int t = threadIdx.x;
  if (t >= 48) return;
  int c = t / 24, g = t % 24;
  const float* qx = c ? qrxb : qrxa;
  const float* qy = c ? qryb : qrya;
  const float* qz = c ? qrzb : qrza;
  float tx = 0.5f*qx[g], ty = 0.5f*qy[g], tz = 0.5f*qz[g];
  float cx = cosf(tx), sx = sinf(tx);
  float cy = cosf(ty), sy = sinf(ty);
  float cz = cosf(tz), sz = sinf(tz);
  C2 rx00{cx,0.f}, rx01{0.f,-sx}, rx10{0.f,-sx}, rx11{cx,0.f};
  C2 m00 = cadd(cmul(C2{cy,0.f},rx00), cmul(C2{-sy,0.f},rx10));
  C2 m01 = cadd(cmul(C2{cy,0.f},rx01), cmul(C2{-sy,0.f},rx11));
  C2 m10 = cadd(cmul(C2{sy,0.f},rx00), cmul(C2{cy,0.f},rx10));
  C2 m11 = cadd(cmul(C2{sy,0.f},rx01), cmul(C2{cy,0.f},rx11));
  C2 e0{cz,-sz}, e1{cz,sz};
  C2 u00 = cmul(e0,m00), u01 = cmul(e0,m01), u10 = cmul(e1,m10), u11 = cmul(e1,m11);
  float* o = gates + (size_t)(c*24 + g)*8;
  o[0]=u00.r; o[1]=u00.i; o[2]=u01.r; o[3]=u01.i;
  o[4]=u10.r; o[5]=u10.i; o[6]=u11.r; o[7]=u11.i;
}

// G[c][n][i] = sum_q sign_q(i) * w3[q][n]   (i contiguous -> B-frag friendly)
__global__ __launch_bounds__(256)
void gprep(const float* __restrict__ w3a, const float* __restrict__ w3b,
           unsigned short* __restrict__ Gm) {
  int idx = blockIdx.x*256 + threadIdx.x;       // 512 blocks -> 131072
  int c = idx >> 16, rem = idx & 65535, n = rem >> 8, i = rem & 255;
  const float* w3 = c ? w3b : w3a;
  float s = 0.f;
  #pragma unroll
  for (int q = 0; q < 8; ++q) {
    float sg = ((i >> (7-q)) & 1) ? -1.f : 1.f;
    s += sg * w3[q*256 + n];
  }
  Gm[(size_t)(c*256 + n)*256 + i] = f2bf(s);
}

#define APPLY2(A,Bx)                                                        \
  { float ar=re[A], ai=im[A], br=re[Bx], bi=im[Bx];                         \
    re[A]  = u00r*ar - u00i*ai + u01r*br - u01i*bi;                         \
    im[A]  = u00r*ai + u00i*ar + u01r*bi + u01i*br;                         \
    re[Bx] = u10r*ar - u10i*ai + u11r*br - u11i*bi;                         \
    im[Bx] = u10r*ai + u10i*ar + u11r*bi + u11i*br; }

// Simulate circuit on basis column bcol (with phase (-i)^popc folded in):
// wave holds psi_i at i = 4*lane + j. Writes Bmat rows: re at n=i, im at n=256+i.
__global__ __launch_bounds__(256)
void prep_W(const float* __restrict__ gates, unsigned short* __restrict__ Bm) {
  __shared__ float sg[384];
  int tid = threadIdx.x;
  for (int i = tid; i < 384; i += 256) sg[i] = gates[i];
  __syncthreads();
  int lane = tid & 63;
  int wid = blockIdx.x*4 + (tid >> 6);   // [0,512)
  int c = wid >> 8, bcol = wid & 255;
  int p = __popc(bcol) & 3;
  float phr = (p==0) ? 1.f : ((p==2) ? -1.f : 0.f);
  float phi = (p==1) ? -1.f : ((p==3) ? 1.f : 0.f);
  float re[4], im[4];
  #pragma unroll
  for (int j = 0; j < 4; ++j) {
    int idx = 4*lane + j;
    re[j] = (idx==bcol) ? phr : 0.f;
    im[j] = (idx==bcol) ? phi : 0.f;
  }
  #pragma unroll
  for (int l = 0; l < 3; ++l) {
    #pragma unroll
    for (int q = 0; q < 8; ++q) {
      const float* u = &sg[(size_t)(c*24 + l*8 + q)*8];
      float u00r=u[0],u00i=u[1],u01r=u[2],u01i=u[3];
      float u10r=u[4],u10i=u[5],u11r=u[6],u11i=u[7];
      if (q < 6) {
        int m = 5-q, mask = 1<<m;
        bool s1 = ((lane >> m) & 1) != 0;
        float udr = s1?u11r:u00r, udi = s1?u11i:u00i;
        float uor = s1?u10r:u01r, uoi = s1?u10i:u01i;
        #pragma unroll
        for (int j = 0; j < 4; ++j) {
          float pr = __shfl_xor(re[j], mask);
          float pi = __shfl_xor(im[j], mask);
          float nr = udr*re[j] - udi*im[j] + uor*pr - uoi*pi;
          float ni = udr*im[j] + udi*re[j] + uor*pi + uoi*pr;
          re[j]=nr; im[j]=ni;
        }
      } else if (q == 6) { APPLY2(0,2); APPLY2(1,3); }
      else               { APPLY2(0,1); APPLY2(2,3); }
    }
    #pragma unroll
    for (int cq = 0; cq <= 4; ++cq) {
      int tmask = 1 << (4-cq);
      bool pred = ((lane >> (5-cq)) & 1) != 0;
      #pragma unroll
      for (int j = 0; j < 4; ++j) {
        float sr = __shfl_xor(re[j], tmask);
        float si = __shfl_xor(im[j], tmask);
        re[j] = pred ? sr : re[j];
        im[j] = pred ? si : im[j];
      }
    }
    { bool pred = (lane & 1) != 0;
      float t0, t1;
      t0 = pred?re[2]:re[0]; t1 = pred?re[0]:re[2]; re[0]=t0; re[2]=t1;
      t0 = pred?im[2]:im[0]; t1 = pred?im[0]:im[2]; im[0]=t0; im[2]=t1;
      t0 = pred?re[3]:re[1]; t1 = pred?re[1]:re[3]; re[1]=t0; re[3]=t1;
      t0 = pred?im[3]:im[1]; t1 = pred?im[1]:im[3]; im[1]=t0; im[3]=t1; }
    { float t;
      t=re[2]; re[2]=re[3]; re[3]=t;
      t=im[2]; im[2]=im[3]; im[3]=t; }
    { re[1]=__shfl_xor(re[1],32); im[1]=__shfl_xor(im[1],32);
      re[3]=__shfl_xor(re[3],32); im[3]=__shfl_xor(im[3],32); }
  }
  #pragma unroll
  for (int j = 0; j < 4; ++j) {
    int i = 4*lane + j;
    Bm[(size_t)(c*512 + i)*256 + bcol]       = f2bf(re[j]);
    Bm[(size_t)(c*512 + 256 + i)*256 + bcol] = f2bf(im[j]);
  }
}

// ---------------------------------------------------------------------------
// enc kernel (unchanged from R1, validated): 64 rows/block fp32 GEMM + w2 epi.
// ---------------------------------------------------------------------------
__global__ __launch_bounds__(256)
void enc_kernel(const float* __restrict__ state, const float* __restrict__ action,
                const float* __restrict__ w1a, const float* __restrict__ b1a,
                const float* __restrict__ w2a, const float* __restrict__ b2a,
                const float* __restrict__ w1b, const float* __restrict__ b1b,
                const float* __restrict__ w2b, const float* __restrict__ b2b,
                float* __restrict__ enc, int B) {
  __shared__ __align__(16) float xs[64*128];
  __shared__ __align__(16) float wsl[32*256];
  __shared__ __align__(16) float w2t[8*256];
  int tid = threadIdx.x;
  int r0 = blockIdx.x * 64;
  int tr = tid >> 5, tc = tid & 31;

  const float4* st4 = (const float4*)state;
  const float4* ac4 = (const float4*)action;
  for (int idx = tid; idx < 64*24; idx += 256) {
    int r = idx / 24, k4 = idx % 24;
    float4 v = st4[(size_t)(r0 + r)*24 + k4];
    ((float4*)&xs[r*128 + k4*4])[0] = v;
  }
  for (int idx = tid; idx < 64*8; idx += 256) {
    int r = idx >> 3, k4 = idx & 7;
    float4 v = ac4[(size_t)(r0 + r)*8 + k4];
    ((float4*)&xs[r*128 + 96 + k4*4])[0] = v;
  }

  for (int c = 0; c < 2; ++c) {
    const float* w1 = c ? w1b : w1a;
    const float* b1 = c ? b1b : b1a;
    const float* w2 = c ? w2b : w2a;
    const float* b2 = c ? b2b : b2a;
    float acc[8][8];
    #pragma unroll
    for (int rr = 0; rr < 8; ++rr)
      #pragma unroll
      for (int cc = 0; cc < 8; ++cc) acc[rr][cc] = 0.f;

    const float4* w1_4 = (const float4*)w1;
    for (int s = 0; s < 4; ++s) {
      __syncthreads();
      #pragma unroll
      for (int j = 0; j < 8; ++j) {
        int idx4 = tid + j*256;
        float4 v = w1_4[s*2048 + idx4];
        ((float4*)&wsl[idx4*4])[0] = v;
      }
      __syncthreads();
      #pragma unroll 4
      for (int kk = 0; kk < 32; ++kk) {
        float av[8], bv[8];
        #pragma unroll
        for (int rr = 0; rr < 8; ++rr) av[rr] = xs[(tr*8+rr)*128 + s*32 + kk];
        const float4* wp = (const float4*)&wsl[kk*256 + tc*8];
        float4 blo = wp[0], bhi = wp[1];
        bv[0]=blo.x; bv[1]=blo.y; bv[2]=blo.z; bv[3]=blo.w;
        bv[4]=bhi.x; bv[5]=bhi.y; bv[6]=bhi.z; bv[7]=bhi.w;
        #pragma unroll
        for (int rr = 0; rr < 8; ++rr)
          #pragma unroll
          for (int cc = 0; cc < 8; ++cc) acc[rr][cc] = fmaf(av[rr], bv[cc], acc[rr][cc]);
      }
    }

    __syncthreads();
    for (int idx = tid; idx < 2048; idx += 256) {
      int n = idx >> 3, e = idx & 7;
      w2t[e*256 + n] = w2[idx];
    }
    __syncthreads();
    float b1v[8];
    #pragma unroll
    for (int cc = 0; cc < 8; ++cc) b1v[cc] = b1[tc*8 + cc];
    #pragma unroll
    for (int rr = 0; rr < 8; ++rr)
      #pragma unroll
      for (int cc = 0; cc < 8; ++cc) acc[rr][cc] = fmaxf(acc[rr][cc] + b1v[cc], 0.f);

    float penc[8][8];
    #pragma unroll
    for (int rr = 0; rr < 8; ++rr)
      #pragma unroll
      for (int e = 0; e < 8; ++e) penc[rr][e] = 0.f;
    #pragma unroll
    for (int e = 0; e < 8; ++e) {
      const float4* wp = (const float4*)&w2t[e*256 + tc*8];
      float4 wlo = wp[0], whi = wp[1];
      float wv[8] = {wlo.x,wlo.y,wlo.z,wlo.w,whi.x,whi.y,whi.z,whi.w};
      #pragma unroll
      for (int rr = 0; rr < 8; ++rr)
        #pragma unroll
        for (int cc = 0; cc < 8; ++cc) penc[rr][e] = fmaf(acc[rr][cc], wv[cc], penc[rr][e]);
    }
    #pragma unroll
    for (int mask = 1; mask <= 16; mask <<= 1)
      #pragma unroll
      for (int rr = 0; rr < 8; ++rr)
        #pragma unroll
        for (int e = 0; e < 8; ++e) penc[rr][e] += __shfl_xor(penc[rr][e], mask);
    if (tc == 0) {
      float b2v[8];
      #pragma unroll
      for (int e = 0; e < 8; ++e) b2v[e] = b2[e];
      #pragma unroll
      for (int rr = 0; rr < 8; ++rr) {
        int row = r0 + tr*8 + rr;
        float4* op = (float4*)(enc + ((size_t)c*B + row)*8);
        op[0] = make_float4(penc[rr][0]+b2v[0], penc[rr][1]+b2v[1],
                            penc[rr][2]+b2v[2], penc[rr][3]+b2v[3]);
        op[1] = make_float4(penc[rr][4]+b2v[4], penc[rr][5]+b2v[5],
                            penc[rr][6]+b2v[6], penc[rr][7]+b2v[7]);
      }
    }
  }
}

// ---------------------------------------------------------------------------
// qgemm: 512 threads = 8 waves. Wave w owns N-tiles {w (re), 8+w (im)} of Psi
// and h2-cols [32w,32w+32). W-frags live in 128 VGPRs/wave for the whole
// kernel. Per 32-row subtile: sincos->cs (LDS), R built straight into
// frag-order LDS, stage-1 MFMA (Psi), P->LDS (frag order, 1040B pitch),
// stage-2 MFMA (P@G), relu/w4/butterfly, cross-wave LDS reduce -> out.
// ---------------------------------------------------------------------------
__global__ __launch_bounds__(512, 2)
void qgemm(const float* __restrict__ enc,
           const unsigned short* __restrict__ Bm, const unsigned short* __restrict__ Gm,
           const float* __restrict__ b3a, const float* __restrict__ w4a, const float* __restrict__ b4a,
           const float* __restrict__ b3b, const float* __restrict__ w4b, const float* __restrict__ b4b,
           float* __restrict__ out, int Bn) {
  __shared__ __align__(16) char Alds[16384];    // 16 ks * 1024
  __shared__ __align__(16) char Plds[16640];    // 16 ks * 1040 (pad vs write conflicts)
  __shared__ __align__(16) float cs[32*18];     // [row][q]{c,s}, pitch 18 floats
  __shared__ float redbuf[8][32];

  int tid = threadIdx.x;
  int lane = tid & 63;
  int w = tid >> 6;                 // wave 0..7
  int il = lane & 31;
  int khalf = (lane >> 5) * 8;

  int bx = blockIdx.x;              // [0, 512)
  int c = bx >> 8;                  // critic
  int rowblock = bx & 255;
  int rowsPerBlock = Bn >> 8;       // 256
  int subtiles = rowsPerBlock >> 5; // 8

  // ---- preload W-frags: tile pair (w, 8+w) ----
  bfrag_t bf0[16], bf1[16];
  {
    const unsigned short* base = Bm + ((size_t)(c*512 + 32*w + il)*256 + khalf);
    #pragma unroll
    for (int ks = 0; ks < 16; ++ks) {
      bf0[ks] = *(const bfrag_t*)(base + ks*16);
      bf1[ks] = *(const bfrag_t*)(base + 256*256 + ks*16);
    }
  }
  int n2 = 32*w + il;
  const float* b3c = c ? b3b : b3a;
  const float* w4c = c ? w4b : w4a;
  const float* b4c = c ? b4b : b4a;
  float b3v = b3c[n2];
  float w4v = w4c[n2];
  float b4v = b4c[0];
  const unsigned short* Gbase = Gm + ((size_t)(c*256 + n2)*256 + khalf);
  // P-write address base (i fixed per lane, stage-1 col)
  int iCol = n2;
  int pwbase = (iCol>>4)*1040 + ((iCol>>3)&1)*512 + (iCol&7)*2;
  int rowAdd = 4*(lane>>5);

  for (int st = 0; st < subtiles; ++st) {
    int r0 = rowblock*rowsPerBlock + st*32;
    __syncthreads();                                   // (a) reuse guard
    // ---- phase A: sincos for 32 rows x 8 qubits ----
    if (tid < 256) {
      int m = tid & 31, q = tid >> 5;
      float e = enc[((size_t)c*Bn + r0 + m)*8 + q];
      float sv, cv;
      __sincosf(0.5f*e, &sv, &cv);
      cs[m*18 + q*2]     = cv;
      cs[m*18 + q*2 + 1] = sv;
    }
    __syncthreads();                                   // (b) cs ready
    // ---- phase B: build R tile in frag-order LDS ----
    {
      int m = tid & 31, g2 = tid >> 5;                 // g2 in [0,16) = ks
      float2 q0 = *(float2*)&cs[m*18 + 0];
      float2 q1 = *(float2*)&cs[m*18 + 2];
      float2 q2 = *(float2*)&cs[m*18 + 4];
      float2 q3 = *(float2*)&cs[m*18 + 6];
      float2 q4 = *(float2*)&cs[m*18 + 8];
      float2 q5 = *(float2*)&cs[m*18 + 10];
      float2 q6 = *(float2*)&cs[m*18 + 12];
      float2 q7 = *(float2*)&cs[m*18 + 14];
      float v0 = (g2&8) ? q0.y : q0.x;                 // qubit0 <- g2 bit3
      float v1 = (g2&4) ? q1.y : q1.x;
      float v2 = (g2&2) ? q2.y : q2.x;
      float v3 = (g2&1) ? q3.y : q3.x;
      float top = v0*v1*v2*v3;
      float hA = top*q4.x, hB = top*q4.y;              // qubit4 = 0 / 1
      float p67[4];
      p67[0] = q6.x*q7.x; p67[1] = q6.x*q7.y;
      p67[2] = q6.y*q7.x; p67[3] = q6.y*q7.y;
      float low[8];
      #pragma unroll
      for (int j = 0; j < 8; ++j) low[j] = ((j&4) ? q5.y : q5.x) * p67[j&3];
      union { bfrag_t v; unsigned u[4]; } pk;
      #pragma unroll
      for (int k = 0; k < 4; ++k) pk.u[k] = pack2(hA*low[2*k], hA*low[2*k+1]);
      *(bfrag_t*)(Alds + g2*1024 + m*16) = pk.v;
      #pragma unroll
      for (int k = 0; k < 4; ++k) pk.u[k] = pack2(hB*low[2*k], hB*low[2*k+1]);
      *(bfrag_t*)(Alds + g2*1024 + 512 + m*16) = pk.v;
    }
    __syncthreads();                                   // (c) A ready
    // ---- stage 1: Psi = R @ W^T ----
    accv_t acc0 = {}, acc1 = {};
    #pragma unroll
    for (int ks = 0; ks < 16; ++ks) {
      bfrag_t af = *(const bfrag_t*)(Alds + ks*1024 + lane*16);
      acc0 = __builtin_amdgcn_mfma_f32_32x32x16_bf16(af, bf0[ks], acc0, 0, 0, 0);
      acc1 = __builtin_amdgcn_mfma_f32_32x32x16_bf16(af, bf1[ks], acc1, 0, 0, 0);
    }
    // ---- P = re^2 + im^2 -> Plds (frag order for stage 2) ----
    #pragma unroll
    for (int r = 0; r < 16; ++r) {
      float P = acc0[r]*acc0[r] + acc1[r]*acc1[r];
      int row = (r&3) + 8*(r>>2) + rowAdd;
      *(unsigned short*)(Plds + pwbase + row*16) = f2bf(P);
    }
    __syncthreads();                                   // (d) P ready
    // ---- stage 2: ex@w3 = P @ G ----
    accv_t acc2 = {};
    #pragma unroll
    for (int ks = 0; ks < 16; ++ks) {
      bfrag_t pf = *(const bfrag_t*)(Plds + ks*1040 + lane*16);
      bfrag_t gf = *(const bfrag_t*)(Gbase + ks*16);
      acc2 = __builtin_amdgcn_mfma_f32_32x32x16_bf16(pf, gf, acc2, 0, 0, 0);
    }
    // ---- epilogue: relu + w4 dot + reduce ----
    float qp[16];
    #pragma unroll
    for (int r = 0; r < 16; ++r) {
      float h2 = fmaxf(acc2[r] + b3v, 0.f);
      qp[r] = h2 * w4v;
    }
    #pragma unroll
    for (int mask = 1; mask <= 16; mask <<= 1)
      #pragma unroll
      for (int r = 0; r < 16; ++r) qp[r] += __shfl_xor(qp[r], mask);
    if (il == 0) {
      #pragma unroll
      for (int r = 0; r < 16; ++r)
        redbuf[w][(r&3) + 8*(r>>2) + rowAdd] = qp[r];
    }
    __syncthreads();                                   // (e) partials ready
    if (tid < 32) {
      float s = b4v;
      #pragma unroll
      for (int ww = 0; ww < 8; ++ww) s += redbuf[ww][tid];
      out[(size_t)c*Bn + r0 + tid] = s;
    }
  }
}

extern "C" void kernel_launch(void* const* d_in, const int* in_sizes, int n_in,
                              void* d_out, int out_size, void* d_ws, size_t ws_size,
                              hipStream_t stream) {
  (void)n_in; (void)out_size; (void)ws_size;
  const float* state  = (const float*)d_in[0];
  const float* action = (const float*)d_in[1];
  const float* w1a=(const float*)d_in[2];  const float* b1a=(const float*)d_in[3];
  const float* w2a=(const float*)d_in[4];  const float* b2a=(const float*)d_in[5];
  const float* qrxa=(const float*)d_in[6]; const float* qrya=(const float*)d_in[7];
  const float* qrza=(const float*)d_in[8];
  const float* w3a=(const float*)d_in[9];  const float* b3a=(const float*)d_in[10];
  const float* w4a=(const float*)d_in[11]; const float* b4a=(const float*)d_in[12];
  const float* w1b=(const float*)d_in[13]; const float* b1b=(const float*)d_in[14];
  const float* w2b=(const float*)d_in[15]; const float* b2b=(const float*)d_in[16];
  const float* qrxb=(const float*)d_in[17];const float* qryb=(const float*)d_in[18];
  const float* qrzb=(const float*)d_in[19];
  const float* w3b=(const float*)d_in[20]; const float* b3b=(const float*)d_in[21];
  const float* w4b=(const float*)d_in[22]; const float* b4b=(const float*)d_in[23];

  int B = in_sizes[0] / 96;
  char* wsb = (char*)d_ws;
  float* gates          = (float*)wsb;                              // 1536 B
  unsigned short* Bmat  = (unsigned short*)(wsb + 4096);            // 524288 B
  unsigned short* Gmat  = (unsigned short*)(wsb + 4096 + 524288);   // 262144 B
  float* enc            = (float*)(wsb + 4096 + 524288 + 262144);   // 2*B*8*4 B

  prep_gates<<<1, 64, 0, stream>>>(qrxa,qrya,qrza,qrxb,qryb,qrzb,gates);
  gprep<<<512, 256, 0, stream>>>(w3a, w3b, Gmat);
  prep_W<<<128, 256, 0, stream>>>(gates, Bmat);
  enc_kernel<<<B/64, 256, 0, stream>>>(state,action,w1a,b1a,w2a,b2a,w1b,b1b,w2b,b2b,enc,B);
  qgemm<<<512, 512, 0, stream>>>(enc, Bmat, Gmat, b3a, w4a, b4a, b3b, w4b, b4b,
                                 (float*)d_out, B);
}